// Round 14
// baseline (226.919 us; speedup 1.0000x reference)
//
#include <hip/hip_runtime.h>
#include <math.h>

#define NB   2048
#define DE   256
#define MEMN 16384
#define CAND_CAP 256
#define FSPL 32
#define FKPS 512
#define FIT  16   // 16 iters x 32 K-rows

typedef __attribute__((ext_vector_type(8)))  short  short8;
typedef __attribute__((ext_vector_type(16))) float  float16;
typedef __attribute__((ext_vector_type(4)))  unsigned uint4v;
typedef __attribute__((ext_vector_type(2)))  unsigned uint2v;

// ---------------- workspace layout (float element offsets), ~51.6 MB (verified fit, round 3) ----------------
static const size_t OFF_QB   = 0;          // 2048*256 bf16
static const size_t OFF_KB   = 262144;     // 16384*256 bf16
static const size_t OFF_VTB  = 2359296;    // Vt tiled [512][256][32] bf16
static const size_t OFF_LP   = 4456448;    // 32*2048 floats
static const size_t OFF_OPB  = 4521984;    // 32*2048*256 bf16
// stats overlay (dead before flash writes Opb), relative to OFF_OPB:
static const size_t SO_A    = 0;        // 65536 raw Z^T Z (atomic accum; memset to 0)
static const size_t SO_MUP  = 131072;   // 64*256 col-sum partials
static const size_t SO_DIST = 147456;   // 2048 -> end 149504 (< Opb 8388608)

__device__ inline unsigned short f2bf(float f) {
  unsigned u = __float_as_uint(f);
  unsigned r = (u + 0x7fffu + ((u >> 16) & 1u)) >> 16;
  return (unsigned short)r;
}
__device__ inline float bf2f(unsigned short s) {
  return __uint_as_float((unsigned)s << 16);
}

// pack two f32 -> one u32 of 2x bf16 (RNE, lo in [15:0]) — bit-identical to f2bf pairs
__device__ inline unsigned cvtpk_bf16(float lo, float hi) {
  unsigned r;
  asm("v_cvt_pk_bf16_f32 %0, %1, %2" : "=v"(r) : "v"(lo), "v"(hi));
  return r;
}
// pack 8 f32 (two float4) into a short8 of bf16 via 4 cvt_pk ops
__device__ inline short8 pack8_bf16(float4 f0, float4 f1) {
  uint4v u = {cvtpk_bf16(f0.x, f0.y), cvtpk_bf16(f0.z, f0.w),
              cvtpk_bf16(f1.x, f1.y), cvtpk_bf16(f1.z, f1.w)};
  return __builtin_bit_cast(short8, u);
}

// exchange lane-halves between a lower-k word and a higher-k word (T12).
__device__ inline void halfswap(unsigned& lo, unsigned& hi, int h) {
#if __has_builtin(__builtin_amdgcn_permlane32_swap)
  (void)h;
  uint2v r = __builtin_amdgcn_permlane32_swap(lo, hi, false, false);
  lo = r.x; hi = r.y;
#else
  unsigned a = (unsigned)__shfl_xor((int)lo, 32, 64);
  unsigned b = (unsigned)__shfl_xor((int)hi, 32, 64);
  unsigned nlo = (h == 0) ? lo : b;
  unsigned nhi = (h == 0) ? a  : hi;
  lo = nlo; hi = nhi;
#endif
}

__device__ inline void bitonic_sort_u64(unsigned long long* key, int n, int tid, int nth) {
  for (int k = 2; k <= n; k <<= 1) {
    for (int j = k >> 1; j > 0; j >>= 1) {
      __syncthreads();
      for (int i = tid; i < n; i += nth) {
        int ixj = i ^ j;
        if (ixj > i) {
          unsigned long long a = key[i], b = key[ixj];
          bool up = ((i & k) == 0);
          if ((a > b) == up) { key[i] = b; key[ixj] = a; }
        }
      }
    }
  }
  __syncthreads();
}

// ---------------- fused stats: cov tiles (flat 0..255) + mean partials (256..319) ----------------
// A must be zeroed beforehand (hipMemsetAsync in launcher).
__global__ __launch_bounds__(256) void covmu_kernel(const float* __restrict__ z,
                                                    float* __restrict__ A,
                                                    float* __restrict__ mup) {
  int f = blockIdx.x;
  int tid = threadIdx.x;
  if (f >= 256) {                  // ---- mean partials ----
    int b = f - 256;
    int r0 = b * 32;
    float s = 0.f;
    for (int r = 0; r < 32; ++r) s += z[(size_t)(r0 + r) * DE + tid];
    mup[b * DE + tid] = s;
    return;
  }
  // ---- Z^T Z 64x64 tile over a 128-row slice, atomicAdd into A ----
  __shared__ float As[16][68];
  __shared__ float Bs[16][68];
  int tx = tid & 15, ty = tid >> 4;
  int i0 = (f & 3) * 64, j0 = ((f >> 2) & 3) * 64;
  int nbase = (f >> 4) * 128;
  float acc[4][4] = {};
  for (int nt = 0; nt < 8; ++nt) {
    int n0 = nbase + nt * 16;
    for (int e = tid; e < 1024; e += 256) {
      int c = e & 63, nn = e >> 6;
      As[nn][c] = z[(size_t)(n0 + nn) * DE + i0 + c];
      Bs[nn][c] = z[(size_t)(n0 + nn) * DE + j0 + c];
    }
    __syncthreads();
#pragma unroll
    for (int nn = 0; nn < 16; ++nn) {
      float4 a4 = *(const float4*)&As[nn][ty * 4];
      float4 b4 = *(const float4*)&Bs[nn][tx * 4];
      acc[0][0] += a4.x*b4.x; acc[0][1] += a4.x*b4.y; acc[0][2] += a4.x*b4.z; acc[0][3] += a4.x*b4.w;
      acc[1][0] += a4.y*b4.x; acc[1][1] += a4.y*b4.y; acc[1][2] += a4.y*b4.z; acc[1][3] += a4.y*b4.w;
      acc[2][0] += a4.z*b4.x; acc[2][1] += a4.z*b4.y; acc[2][2] += a4.z*b4.z; acc[2][3] += a4.z*b4.w;
      acc[3][0] += a4.w*b4.x; acc[3][1] += a4.w*b4.y; acc[3][2] += a4.w*b4.z; acc[3][3] += a4.w*b4.w;
    }
    __syncthreads();
  }
  for (int r = 0; r < 4; ++r) {
    int i = i0 + ty * 4 + r;
    for (int c = 0; c < 4; ++c) {
      int j = j0 + tx * 4 + c;
      atomicAdd(&A[(size_t)i * DE + j], acc[r][c]);
    }
  }
}

// ---------------- dist: Mahalanobis via quadratic form, E built on-the-fly ----------------
// d = c^T X c with X = I + E + E^2  ==  c.c + c.u + u.u where u = E c (E symmetric).
// E[j][i] = -(0.99 rcov[j][i] + c1 (ZtZ[j][i] - mus_j mus_i / N)) + (j==i)(1-1e-6).
// Replaces the old gemmx (X materialization) + dist pair: one fewer serial launch.
// 8 rows per block, grid 256.
__global__ __launch_bounds__(256) void dist_kernel(const float* __restrict__ z,
                                                   const float* __restrict__ rmean,
                                                   const float* __restrict__ mup,
                                                   const float* __restrict__ ZtZ,
                                                   const float* __restrict__ rcov,
                                                   float* __restrict__ dist) {
  __shared__ float cc[8][256];
  __shared__ float mus[256];
  __shared__ float4 red[256];
  int n0 = blockIdx.x * 8, i = threadIdx.x;
  float s = 0.f;
  for (int b = 0; b < 64; ++b) s += mup[b * DE + i];
  mus[i] = s;
  float rmi = 0.99f * rmean[i] + 0.01f * s * (1.0f / (float)NB);
#pragma unroll
  for (int r = 0; r < 8; ++r) cc[r][i] = z[(size_t)(n0 + r) * DE + i] - rmi;
  __syncthreads();
  const float c1 = 0.01f / (float)(NB - 1);
  const float invN = 1.0f / (float)NB;
  float musi = mus[i];
  float u[8] = {};
#pragma unroll 4
  for (int j = 0; j < DE; ++j) {
    float base = 0.99f * rcov[(size_t)j * DE + i] +
                 c1 * (ZtZ[(size_t)j * DE + i] - mus[j] * musi * invN);
    float e = -base;
    if (j == i) e += 1.0f - 1e-6f;
#pragma unroll
    for (int r = 0; r < 8; ++r) u[r] += e * cc[r][j];
  }
  // rows 0..3
  {
    float4 v;
    v.x = cc[0][i] * (cc[0][i] + u[0]) + u[0] * u[0];
    v.y = cc[1][i] * (cc[1][i] + u[1]) + u[1] * u[1];
    v.z = cc[2][i] * (cc[2][i] + u[2]) + u[2] * u[2];
    v.w = cc[3][i] * (cc[3][i] + u[3]) + u[3] * u[3];
    red[i] = v;
    __syncthreads();
    for (int sH = 128; sH > 0; sH >>= 1) {
      if (i < sH) {
        float4 a = red[i], b = red[i + sH];
        a.x += b.x; a.y += b.y; a.z += b.z; a.w += b.w;
        red[i] = a;
      }
      __syncthreads();
    }
    if (i < 4) {
      float4 tt = red[0];
      float d = (i == 0) ? tt.x : (i == 1) ? tt.y : (i == 2) ? tt.z : tt.w;
      dist[n0 + i] = sqrtf(fmaxf(d, 1e-8f));
    }
    __syncthreads();
  }
  // rows 4..7
  {
    float4 v;
    v.x = cc[4][i] * (cc[4][i] + u[4]) + u[4] * u[4];
    v.y = cc[5][i] * (cc[5][i] + u[5]) + u[5] * u[5];
    v.z = cc[6][i] * (cc[6][i] + u[6]) + u[6] * u[6];
    v.w = cc[7][i] * (cc[7][i] + u[7]) + u[7] * u[7];
    red[i] = v;
    __syncthreads();
    for (int sH = 128; sH > 0; sH >>= 1) {
      if (i < sH) {
        float4 a = red[i], b = red[i + sH];
        a.x += b.x; a.y += b.y; a.z += b.z; a.w += b.w;
        red[i] = a;
      }
      __syncthreads();
    }
    if (i < 4) {
      float4 tt = red[0];
      float d = (i == 0) ? tt.x : (i == 1) ? tt.y : (i == 2) ? tt.z : tt.w;
      dist[n0 + 4 + i] = sqrtf(fmaxf(d, 1e-8f));
    }
  }
}

// ---------------- fused update: wave reductions, small-C wave sort, two-level extraction ----------------
__global__ __launch_bounds__(1024) void update_kernel(const float* __restrict__ dist,
                                                      const int* __restrict__ labels,
                                                      const float* __restrict__ weights,
                                                      const float* __restrict__ z,
                                                      float* __restrict__ memory) {
  __shared__ unsigned long long ikeys[NB];
  __shared__ unsigned long long ck[CAND_CAP];
  __shared__ unsigned long long gmin[16];
  __shared__ int slots[CAND_CAP], srcs[CAND_CAP];
  __shared__ float smin[16], smax[16];
  __shared__ int scnt[16];
  __shared__ float s_kl, s_dmin, s_inv;
  __shared__ int s_ccnt, s_m, s_stop, s_bg;
  int t = threadIdx.x;
  int wid = t >> 6, lane = t & 63;

  float mn = 1e30f, mx = -1e30f; int c1 = 0;
  for (int n = t; n < NB; n += 1024) {
    float d = dist[n];
    mn = fminf(mn, d); mx = fmaxf(mx, d);
    c1 += labels[n];
  }
#pragma unroll
  for (int o = 32; o > 0; o >>= 1) {
    mn = fminf(mn, __shfl_xor(mn, o, 64));
    mx = fmaxf(mx, __shfl_xor(mx, o, 64));
    c1 += __shfl_xor(c1, o, 64);
  }
  if (lane == 0) { smin[wid] = mn; smax[wid] = mx; scnt[wid] = c1; }
  if (t == 0) { s_ccnt = 0; s_m = 0; s_stop = 0; }
  __syncthreads();
  if (t == 0) {
    float a = 1e30f, b = -1e30f; int cc = 0;
    for (int i = 0; i < 16; ++i) { a = fminf(a, smin[i]); b = fmaxf(b, smax[i]); cc += scnt[i]; }
    float p1 = (float)cc / (float)NB;
    float p0 = (float)(NB - cc) / (float)NB;
    float kl = p0 * logf(fmaxf(2.f * p0, 1e-8f)) + p1 * logf(fmaxf(2.f * p1, 1e-8f));
    s_kl = fmaxf(kl, 0.f);
    s_dmin = a;
    s_inv = 1.0f / (b - a + 1e-8f);
  }
  __syncthreads();
  float kl = s_kl;

  for (int n = t; n < NB; n += 1024) {
    float imp = (1.0f + (dist[n] - s_dmin) * s_inv) * kl;
    ikeys[n] = ((unsigned long long)(unsigned)(~__float_as_uint(imp)) << 32) | (unsigned)n;
  }
  float thresh = 2.f * kl;
  for (int j = t; j < MEMN; j += 1024) {
    float wv = weights[j];
    if (wv < thresh) {
      int p = atomicAdd(&s_ccnt, 1);
      if (p < CAND_CAP) ck[p] = ((unsigned long long)__float_as_uint(wv) << 32) | (unsigned)j;
    }
  }
  __syncthreads();
  int C = s_ccnt; if (C > CAND_CAP) C = CAND_CAP;
  for (int i = t; i < CAND_CAP; i += 1024)
    if (i >= C) ck[i] = 0xFFFFFFFFFFFFFFFFULL;
  __syncthreads();
  if (C <= 64) {
    // single-wave rank sort, no barriers inside (wave 0 only)
    if (wid == 0) {
      unsigned long long key = (lane < C) ? ck[lane] : 0xFFFFFFFFFFFFFFFFULL;
      int rank = 0;
      for (int j = 0; j < 64; ++j) {
        unsigned long long o = (unsigned long long)__shfl((long long)key, j, 64);
        rank += (o < key) || (o == key && j < lane);
      }
      if (lane < C) ck[rank] = key;
    }
    __syncthreads();
  } else {
    bitonic_sort_u64(ck, CAND_CAP, t, 1024);
  }

  // group minima: wave wid owns ikeys[wid*128 .. wid*128+127]
  {
    unsigned long long a = ikeys[wid * 128 + lane];
    unsigned long long b = ikeys[wid * 128 + 64 + lane];
    unsigned long long mm = a < b ? a : b;
#pragma unroll
    for (int o = 32; o > 0; o >>= 1) {
      unsigned long long ot = (unsigned long long)__shfl_xor((long long)mm, o, 64);
      if (ot < mm) mm = ot;
    }
    if (lane == 0) gmin[wid] = mm;
  }
  __syncthreads();

  float prevv = 0.f;   // thread 0 only
  for (int i = 0; i < C; ++i) {
    if (t == 0) {
      unsigned long long best = 0xFFFFFFFFFFFFFFFFULL;
      for (int g = 0; g < 16; ++g) if (gmin[g] < best) best = gmin[g];
      float im = __uint_as_float(~(unsigned)(best >> 32));
      float wv = __uint_as_float((unsigned)(ck[i] >> 32));
      bool ok = (im > wv) && (i == 0 || prevv >= wv);
      if (ok) {
        int idx = (int)(best & 0xffffffffULL);
        slots[s_m] = (int)(ck[i] & 0xffffffffULL);
        srcs[s_m]  = idx;
        s_m++;
        prevv = im;
        ikeys[idx] = 0xFFFFFFFFFFFFFFFFULL;
        s_bg = idx >> 7;
      } else {
        s_stop = 1; s_bg = -1;
      }
    }
    __syncthreads();
    if (s_stop) break;
    if (wid == s_bg) {
      unsigned long long a = ikeys[wid * 128 + lane];
      unsigned long long b = ikeys[wid * 128 + 64 + lane];
      unsigned long long mm = a < b ? a : b;
#pragma unroll
      for (int o = 32; o > 0; o >>= 1) {
        unsigned long long ot = (unsigned long long)__shfl_xor((long long)mm, o, 64);
        if (ot < mm) mm = ot;
      }
      if (lane == 0) gmin[wid] = mm;
    }
    __syncthreads();
  }
  int m = s_m;
  for (int e = t; e < m * DE; e += 1024) {
    int i = e >> 8, d = e & 255;
    memory[(size_t)slots[i] * DE + d] = z[(size_t)srcs[i] * DE + d];
  }
}

// ---------------- fused Q/K/V projection GEMMs — A/B-reuse structure (round-12, verified) ----------------
__global__ __launch_bounds__(256, 1) void qkv_kernel(
    const float* __restrict__ z, const float* __restrict__ memory,
    const float* __restrict__ Wq, const float* __restrict__ bq,
    const float* __restrict__ Wk, const float* __restrict__ bk,
    const float* __restrict__ Wv, const float* __restrict__ bv,
    unsigned short* __restrict__ Qbf, unsigned short* __restrict__ Kbf,
    unsigned short* __restrict__ Vtb) {
  __shared__ unsigned short Bsh[64 * 264];
  int flat = blockIdx.x;
  int tid = threadIdx.x;
  int w = tid >> 6, lane = tid & 63;
  int m = lane & 31, h = lane >> 5;

  if (flat < 64) {                 // ---- Q = z@Wq^T+bq (16x4 tiles) ----
    int gx = flat & 15, gy = flat >> 4;
    int arow = gx * 128 + w * 32 + m;
    int n0 = gy * 64;
    short8 af[16];
#pragma unroll
    for (int kc = 0; kc < 16; ++kc) {
      const float* src = &z[(size_t)arow * DE + kc * 16 + h * 8];
      af[kc] = pack8_bf16(*(const float4*)&src[0], *(const float4*)&src[4]);
    }
    {
      int r = tid >> 2, q = tid & 3;
      const float* src = &Wq[(size_t)(n0 + r) * DE + q * 64];
      unsigned short* dst = &Bsh[r * 264 + q * 64];
#pragma unroll
      for (int j = 0; j < 8; ++j)
        *(short8*)&dst[j * 8] = pack8_bf16(*(const float4*)&src[j * 8],
                                           *(const float4*)&src[j * 8 + 4]);
    }
    __syncthreads();
    float16 a0 = {}, a1 = {};
#pragma unroll
    for (int kc = 0; kc < 16; ++kc) {
      short8 b0 = *(const short8*)&Bsh[(0 * 32 + m) * 264 + kc * 16 + h * 8];
      short8 b1 = *(const short8*)&Bsh[(1 * 32 + m) * 264 + kc * 16 + h * 8];
      a0 = __builtin_amdgcn_mfma_f32_32x32x16_bf16(af[kc], b0, a0, 0, 0, 0);
      a1 = __builtin_amdgcn_mfma_f32_32x32x16_bf16(af[kc], b1, a1, 0, 0, 0);
    }
#pragma unroll
    for (int r = 0; r < 16; ++r) {
      int rr = (r & 3) + 8 * (r >> 2) + 4 * h;
      int orow = gx * 128 + w * 32 + rr;
      int oc0 = n0 + m, oc1 = n0 + 32 + m;
      Qbf[(size_t)orow * DE + oc0] = f2bf(a0[r] + bq[oc0]);
      Qbf[(size_t)orow * DE + oc1] = f2bf(a1[r] + bq[oc1]);
    }
  } else if (flat < 192) {         // ---- K = mem@Wk^T+bk: A once, loop 4 B-tiles ----
    int gx = flat - 64;            // 0..127
    int arow = gx * 128 + w * 32 + m;
    short8 af[16];
#pragma unroll
    for (int kc = 0; kc < 16; ++kc) {
      const float* src = &memory[(size_t)arow * DE + kc * 16 + h * 8];
      af[kc] = pack8_bf16(*(const float4*)&src[0], *(const float4*)&src[4]);
    }
    for (int g4 = 0; g4 < 4; ++g4) {
      int n0 = g4 * 64;
      __syncthreads();             // previous tile's reads complete
      {
        int r = tid >> 2, q = tid & 3;
        const float* src = &Wk[(size_t)(n0 + r) * DE + q * 64];
        unsigned short* dst = &Bsh[r * 264 + q * 64];
#pragma unroll
        for (int j = 0; j < 8; ++j)
          *(short8*)&dst[j * 8] = pack8_bf16(*(const float4*)&src[j * 8],
                                             *(const float4*)&src[j * 8 + 4]);
      }
      __syncthreads();
      float16 a0 = {}, a1 = {};
#pragma unroll
      for (int kc = 0; kc < 16; ++kc) {
        short8 b0 = *(const short8*)&Bsh[(0 * 32 + m) * 264 + kc * 16 + h * 8];
        short8 b1 = *(const short8*)&Bsh[(1 * 32 + m) * 264 + kc * 16 + h * 8];
        a0 = __builtin_amdgcn_mfma_f32_32x32x16_bf16(af[kc], b0, a0, 0, 0, 0);
        a1 = __builtin_amdgcn_mfma_f32_32x32x16_bf16(af[kc], b1, a1, 0, 0, 0);
      }
#pragma unroll
      for (int r = 0; r < 16; ++r) {
        int rr = (r & 3) + 8 * (r >> 2) + 4 * h;
        int orow = gx * 128 + w * 32 + rr;
        int oc0 = n0 + m, oc1 = n0 + 32 + m;
        Kbf[(size_t)orow * DE + oc0] = f2bf(a0[r] + bk[oc0]);
        Kbf[(size_t)orow * DE + oc1] = f2bf(a1[r] + bk[oc1]);
      }
    }
  } else {                         // ---- Vt = Wv@mem^T+bv: B once, loop 2 A-halves ----
    int gy = flat - 192;           // 0..255
    int n0 = gy * 64;
    {
      int r = tid >> 2, q = tid & 3;
      const float* src = &memory[(size_t)(n0 + r) * DE + q * 64];
      unsigned short* dst = &Bsh[r * 264 + q * 64];
#pragma unroll
      for (int j = 0; j < 8; ++j)
        *(short8*)&dst[j * 8] = pack8_bf16(*(const float4*)&src[j * 8],
                                           *(const float4*)&src[j * 8 + 4]);
    }
    __syncthreads();
    for (int gxv = 0; gxv < 2; ++gxv) {
      short8 af[16];
#pragma unroll
      for (int kc = 0; kc < 16; ++kc) {
        const float* src = &Wv[(size_t)(gxv * 128 + w * 32 + m) * DE + kc * 16 + h * 8];
        af[kc] = pack8_bf16(*(const float4*)&src[0], *(const float4*)&src[4]);
      }
      float16 a0 = {}, a1 = {};
#pragma unroll
      for (int kc = 0; kc < 16; ++kc) {
        short8 b0 = *(const short8*)&Bsh[(0 * 32 + m) * 264 + kc * 16 + h * 8];
        short8 b1 = *(const short8*)&Bsh[(1 * 32 + m) * 264 + kc * 16 + h * 8];
        a0 = __builtin_amdgcn_mfma_f32_32x32x16_bf16(af[kc], b0, a0, 0, 0, 0);
        a1 = __builtin_amdgcn_mfma_f32_32x32x16_bf16(af[kc], b1, a1, 0, 0, 0);
      }
#pragma unroll
      for (int r = 0; r < 16; ++r) {
        int rr = (r & 3) + 8 * (r >> 2) + 4 * h;
        int orow = gxv * 128 + w * 32 + rr;
        int oc0 = n0 + m, oc1 = n0 + 32 + m;
        Vtb[(size_t)(oc0 >> 5) * 8192 + (size_t)orow * 32 + (oc0 & 31)] = f2bf(a0[r] + bv[orow]);
        Vtb[(size_t)(oc1 >> 5) * 8192 + (size_t)orow * 32 + (oc1 & 31)] = f2bf(a1[r] + bv[orow]);
      }
    }
  }
}

// ---------------- MFMA flash attention: dh-merged, FSPL=32, T12 in-reg softmax ----------------
// Round-9 structure (best measured). 264-pad Ks layout retained.
__global__ __launch_bounds__(512, 2) void flash_kernel(
    const unsigned short* __restrict__ Qb, const unsigned short* __restrict__ Kb,
    const unsigned short* __restrict__ Vtb, unsigned short* __restrict__ Opb,
    float* __restrict__ Lp) {
  __shared__ unsigned short Ks[32 * 264];
  __shared__ unsigned short Vs[256 * 40];

  int tid = threadIdx.x;
  int w = tid >> 6, lane = tid & 63;
  int m = lane & 31, h = lane >> 5;
  int sp = blockIdx.x, qg = blockIdx.y;
  int myrow = qg * 256 + w * 32 + m;

  short8 qf[16];
#pragma unroll
  for (int kc = 0; kc < 16; ++kc)
    qf[kc] = *(const short8*)&Qb[(size_t)myrow * DE + kc * 16 + h * 8];

  float16 O[8] = {};
  float lacc = 0.f;

  short8 kreg[2], vreg[2];
#define LOAD_TILES(kb_)                                                              \
  {                                                                                  \
    int kb = (kb_);                                                                  \
    _Pragma("unroll")                                                                \
    for (int i = 0; i < 2; ++i) {                                                    \
      int c = i * 512 + tid, kr = c >> 5, kcol = c & 31;                             \
      kreg[i] = *(const short8*)&Kb[(size_t)(kb + kr) * DE + kcol * 8];              \
    }                                                                                \
    const unsigned short* vg = &Vtb[(size_t)((kb) >> 5) * 8192];                     \
    _Pragma("unroll")                                                                \
    for (int i = 0; i < 2; ++i) {                                                    \
      int c = i * 512 + tid;                                                         \
      vreg[i] = *(const short8*)&vg[c * 8];                                          \
    }                                                                                \
  }
#define STORE_TILES()                                                                \
  {                                                                                  \
    _Pragma("unroll")                                                                \
    for (int i = 0; i < 2; ++i) {                                                    \
      int c = i * 512 + tid, kr = c >> 5, kcol = c & 31;                             \
      *(short8*)&Ks[kr * 264 + kcol * 8] = kreg[i];                                  \
    }                                                                                \
    _Pragma("unroll")                                                                \
    for (int i = 0; i < 2; ++i) {                                                    \
      int c = i * 512 + tid, dr = c >> 2, dc = c & 3;                                \
      *(short8*)&Vs[dr * 40 + dc * 8] = vreg[i];                                     \
    }                                                                                \
  }

  LOAD_TILES(sp * FKPS);

  for (int it = 0; it < FIT; ++it) {
    __syncthreads();               // LDS free (previous compute done)
    STORE_TILES();
    if (it + 1 < FIT) LOAD_TILES(sp * FKPS + (it + 1) * 32);
    __syncthreads();               // LDS ready

    // QK^T with SWAPPED operands: A=K-frag, B=Q-frag -> lane (m,h) holds
    // S[k=crow(r,h)][qrow=m]: the P-row of q-row m is lane-local.
    float16 s = {};
    __builtin_amdgcn_s_setprio(1);
#pragma unroll
    for (int kc = 0; kc < 16; ++kc) {
      short8 b0 = *(const short8*)&Ks[m * 264 + kc * 16 + h * 8];
      s = __builtin_amdgcn_mfma_f32_32x32x16_bf16(b0, qf[kc], s, 0, 0, 0);
    }
    __builtin_amdgcn_s_setprio(0);

    // p[r] = P[m][k=crow(r,h)]; exp(0.625*s - 11.0903549) == exp2(0.90168440*s - 16)
    float p[16];
#pragma unroll
    for (int r = 0; r < 16; ++r)
      p[r] = exp2f(fmaf(s[r], 0.90168440f, -16.0f));

    lacc += ((p[0] + p[1]) + (p[2] + p[3])) + ((p[4] + p[5]) + (p[6] + p[7])) +
            ((p[8] + p[9]) + (p[10] + p[11])) + ((p[12] + p[13]) + (p[14] + p[15]));

    unsigned c0 = cvtpk_bf16(p[0],  p[1]);
    unsigned c1 = cvtpk_bf16(p[2],  p[3]);
    unsigned c2 = cvtpk_bf16(p[4],  p[5]);
    unsigned c3 = cvtpk_bf16(p[6],  p[7]);
    unsigned c4 = cvtpk_bf16(p[8],  p[9]);
    unsigned c5 = cvtpk_bf16(p[10], p[11]);
    unsigned c6 = cvtpk_bf16(p[12], p[13]);
    unsigned c7 = cvtpk_bf16(p[14], p[15]);
    halfswap(c0, c2, h);
    halfswap(c1, c3, h);
    halfswap(c4, c6, h);
    halfswap(c5, c7, h);
    uint4v w0v = {c0, c1, c2, c3};
    uint4v w1v = {c4, c5, c6, c7};
    short8 pa0 = __builtin_bit_cast(short8, w0v);
    short8 pa1 = __builtin_bit_cast(short8, w1v);

    __builtin_amdgcn_s_setprio(1);
#pragma unroll
    for (int ct = 0; ct < 8; ++ct) {
      short8 vb0 = *(const short8*)&Vs[(ct * 32 + m) * 40 + h * 8];
      short8 vb1 = *(const short8*)&Vs[(ct * 32 + m) * 40 + 16 + h * 8];
      O[ct] = __builtin_amdgcn_mfma_f32_32x32x16_bf16(pa0, vb0, O[ct], 0, 0, 0);
      O[ct] = __builtin_amdgcn_mfma_f32_32x32x16_bf16(pa1, vb1, O[ct], 0, 0, 0);
    }
    __builtin_amdgcn_s_setprio(0);
  }
#undef LOAD_TILES
#undef STORE_TILES

  size_t ob = ((size_t)sp * NB + qg * 256 + w * 32) * DE;
#pragma unroll
  for (int ct = 0; ct < 8; ++ct)
#pragma unroll
    for (int r = 0; r < 16; ++r) {
      int rr = (r & 3) + 8 * (r >> 2) + 4 * h;
      Opb[ob + (size_t)rr * DE + ct * 32 + m] = f2bf(O[ct][r]);
    }
  float ltot = lacc + __shfl_xor(lacc, 32, 64);
  if (h == 0)
    Lp[sp * NB + qg * 256 + w * 32 + m] = ltot;
}

// combine: vectorized short8 Opb reads (16 B/lane), 8 rows/block, grid 256.
__global__ __launch_bounds__(256) void combine_kernel(const float* __restrict__ z,
                                                      const unsigned short* __restrict__ Opb,
                                                      const float* __restrict__ Lp,
                                                      float* __restrict__ out) {
  int t = threadIdx.x;
  int n = blockIdx.x * 8 + (t >> 5);
  int c0 = (t & 31) * 8;
  float num[8] = {};
  float den = 0.f;
#pragma unroll
  for (int s = 0; s < FSPL; ++s) {
    den += Lp[s * NB + n];
    short8 v = *(const short8*)&Opb[((size_t)s * NB + n) * DE + c0];
#pragma unroll
    for (int j = 0; j < 8; ++j) num[j] += bf2f((unsigned short)v[j]);
  }
  size_t base = (size_t)n * DE + c0;
  float4 o0, o1;
  o0.x = z[base + 0] + 0.5f * num[0] / den;
  o0.y = z[base + 1] + 0.5f * num[1] / den;
  o0.z = z[base + 2] + 0.5f * num[2] / den;
  o0.w = z[base + 3] + 0.5f * num[3] / den;
  o1.x = z[base + 4] + 0.5f * num[4] / den;
  o1.y = z[base + 5] + 0.5f * num[5] / den;
  o1.z = z[base + 6] + 0.5f * num[6] / den;
  o1.w = z[base + 7] + 0.5f * num[7] / den;
  *(float4*)&out[base] = o0;
  *(float4*)&out[base + 4] = o1;
}

// ---------------- launcher: memset + 6 kernels, stream-ordered ----------------
extern "C" void kernel_launch(void* const* d_in, const int* in_sizes, int n_in,
                              void* d_out, int out_size, void* d_ws, size_t ws_size,
                              hipStream_t stream) {
  (void)in_sizes; (void)n_in; (void)out_size; (void)ws_size;
  const float* z       = (const float*)d_in[0];
  const int*   labels  = (const int*)d_in[1];
  float*       memory  = (float*)d_in[2];
  const float* weights = (const float*)d_in[3];
  const float* rmean   = (const float*)d_in[4];
  const float* rcov    = (const float*)d_in[5];
  const float* Wq      = (const float*)d_in[6];
  const float* bq      = (const float*)d_in[7];
  const float* Wk      = (const float*)d_in[8];
  const float* bk      = (const float*)d_in[9];
  const float* Wv      = (const float*)d_in[10];
  const float* bv      = (const float*)d_in[11];
  float* out = (float*)d_out;
  float* ws  = (float*)d_ws;

  unsigned short* Qbf = (unsigned short*)(ws + OFF_QB);
  unsigned short* Kbf = (unsigned short*)(ws + OFF_KB);
  unsigned short* Vtb = (unsigned short*)(ws + OFF_VTB);
  float* Lp           = ws + OFF_LP;
  unsigned short* Opb = (unsigned short*)(ws + OFF_OPB);
  float* SB    = ws + OFF_OPB;    // stats overlay (dead before flash writes Opb)
  float* A     = SB + SO_A;
  float* mup   = SB + SO_MUP;
  float* dist  = SB + SO_DIST;

  hipMemsetAsync(A, 0, (size_t)DE * DE * sizeof(float), stream);
  covmu_kernel<<<320, 256, 0, stream>>>(z, A, mup);
  dist_kernel<<<NB / 8, 256, 0, stream>>>(z, rmean, mup, A, rcov, dist);
  update_kernel<<<1, 1024, 0, stream>>>(dist, labels, weights, z, memory);
  qkv_kernel<<<448, 256, 0, stream>>>(z, memory, Wq, bq, Wk, bk, Wv, bv, Qbf, Kbf, Vtb);
  flash_kernel<<<dim3(FSPL, NB / 256), 512, 0, stream>>>(Qbf, Kbf, Vtb, Opb, Lp);
  combine_kernel<<<NB / 8, 256, 0, stream>>>(z, Opb, Lp, out);
}

// Round 15
// 214.557 us; speedup vs baseline: 1.0576x; 1.0576x over previous
//
#include <hip/hip_runtime.h>
#include <math.h>

#define NB   2048
#define DE   256
#define MEMN 16384
#define CAND_CAP 256
#define FSPL 32
#define FKPS 512
#define FIT  16   // 16 iters x 32 K-rows

typedef __attribute__((ext_vector_type(8)))  short  short8;
typedef __attribute__((ext_vector_type(16))) float  float16;
typedef __attribute__((ext_vector_type(4)))  unsigned uint4v;
typedef __attribute__((ext_vector_type(2)))  unsigned uint2v;

// ---------------- workspace layout (float element offsets), ~51.6 MB (verified fit, round 3) ----------------
static const size_t OFF_QB   = 0;          // 2048*256 bf16
static const size_t OFF_KB   = 262144;     // 16384*256 bf16
static const size_t OFF_VTB  = 2359296;    // Vt tiled [512][256][32] bf16
static const size_t OFF_LP   = 4456448;    // 32*2048 floats
static const size_t OFF_OPB  = 4521984;    // 32*2048*256 bf16
// stats overlay (dead before flash writes Opb), relative to OFF_OPB (4194304 floats):
static const size_t SO_APART = 0;          // 16*65536 cov partials (no atomics)
static const size_t SO_A     = 1048576;    // 65536 reduced Z^T Z
static const size_t SO_MUP   = 1114112;    // 64*256 col-sum partials
static const size_t SO_DIST  = 1130496;    // 2048 -> end 1132544 (< 4194304)

__device__ inline unsigned short f2bf(float f) {
  unsigned u = __float_as_uint(f);
  unsigned r = (u + 0x7fffu + ((u >> 16) & 1u)) >> 16;
  return (unsigned short)r;
}
__device__ inline float bf2f(unsigned short s) {
  return __uint_as_float((unsigned)s << 16);
}

// pack two f32 -> one u32 of 2x bf16 (RNE, lo in [15:0]) — bit-identical to f2bf pairs
__device__ inline unsigned cvtpk_bf16(float lo, float hi) {
  unsigned r;
  asm("v_cvt_pk_bf16_f32 %0, %1, %2" : "=v"(r) : "v"(lo), "v"(hi));
  return r;
}
// pack 8 f32 (two float4) into a short8 of bf16 via 4 cvt_pk ops
__device__ inline short8 pack8_bf16(float4 f0, float4 f1) {
  uint4v u = {cvtpk_bf16(f0.x, f0.y), cvtpk_bf16(f0.z, f0.w),
              cvtpk_bf16(f1.x, f1.y), cvtpk_bf16(f1.z, f1.w)};
  return __builtin_bit_cast(short8, u);
}

// exchange lane-halves between a lower-k word and a higher-k word (T12).
__device__ inline void halfswap(unsigned& lo, unsigned& hi, int h) {
#if __has_builtin(__builtin_amdgcn_permlane32_swap)
  (void)h;
  uint2v r = __builtin_amdgcn_permlane32_swap(lo, hi, false, false);
  lo = r.x; hi = r.y;
#else
  unsigned a = (unsigned)__shfl_xor((int)lo, 32, 64);
  unsigned b = (unsigned)__shfl_xor((int)hi, 32, 64);
  unsigned nlo = (h == 0) ? lo : b;
  unsigned nhi = (h == 0) ? a  : hi;
  lo = nlo; hi = nhi;
#endif
}

__device__ inline void bitonic_sort_u64(unsigned long long* key, int n, int tid, int nth) {
  for (int k = 2; k <= n; k <<= 1) {
    for (int j = k >> 1; j > 0; j >>= 1) {
      __syncthreads();
      for (int i = tid; i < n; i += nth) {
        int ixj = i ^ j;
        if (ixj > i) {
          unsigned long long a = key[i], b = key[ixj];
          bool up = ((i & k) == 0);
          if ((a > b) == up) { key[i] = b; key[ixj] = a; }
        }
      }
    }
  }
  __syncthreads();
}

// ---------------- fused stats + Q-projection (flat roles) ----------------
// f in [0,256): Z^T Z 64x64 tile over a 128-row slice -> PLAIN store to A_part
//   (round-15: the old atomicAdd version issued 1M device-scope atomics with
//    16-way cross-XCD address sharing — the suspected hidden pool cost).
// f in [256,320): mean partials.
// f in [320,384): Q = z@Wq^T+bq (depends only on inputs; folded into launch 1).
__global__ __launch_bounds__(256) void covmu_kernel(const float* __restrict__ z,
                                                    float* __restrict__ Apart,
                                                    float* __restrict__ mup,
                                                    const float* __restrict__ Wq,
                                                    const float* __restrict__ bq,
                                                    unsigned short* __restrict__ Qbf) {
  int f = blockIdx.x;
  int tid = threadIdx.x;
  if (f >= 320) {                  // ---- Q projection ----
    __shared__ unsigned short Bsh[64 * 264];
    int g = f - 320;
    int gx = g & 15, gy = g >> 4;
    int w = tid >> 6, lane = tid & 63;
    int m = lane & 31, h = lane >> 5;
    int arow = gx * 128 + w * 32 + m;
    int n0 = gy * 64;
    short8 af[16];
#pragma unroll
    for (int kc = 0; kc < 16; ++kc) {
      const float* src = &z[(size_t)arow * DE + kc * 16 + h * 8];
      af[kc] = pack8_bf16(*(const float4*)&src[0], *(const float4*)&src[4]);
    }
    {
      int r = tid >> 2, q = tid & 3;
      const float* src = &Wq[(size_t)(n0 + r) * DE + q * 64];
      unsigned short* dst = &Bsh[r * 264 + q * 64];
#pragma unroll
      for (int j = 0; j < 8; ++j)
        *(short8*)&dst[j * 8] = pack8_bf16(*(const float4*)&src[j * 8],
                                           *(const float4*)&src[j * 8 + 4]);
    }
    __syncthreads();
    float16 a0 = {}, a1 = {};
#pragma unroll
    for (int kc = 0; kc < 16; ++kc) {
      short8 b0 = *(const short8*)&Bsh[(0 * 32 + m) * 264 + kc * 16 + h * 8];
      short8 b1 = *(const short8*)&Bsh[(1 * 32 + m) * 264 + kc * 16 + h * 8];
      a0 = __builtin_amdgcn_mfma_f32_32x32x16_bf16(af[kc], b0, a0, 0, 0, 0);
      a1 = __builtin_amdgcn_mfma_f32_32x32x16_bf16(af[kc], b1, a1, 0, 0, 0);
    }
#pragma unroll
    for (int r = 0; r < 16; ++r) {
      int rr = (r & 3) + 8 * (r >> 2) + 4 * h;
      int orow = gx * 128 + w * 32 + rr;
      int oc0 = n0 + m, oc1 = n0 + 32 + m;
      Qbf[(size_t)orow * DE + oc0] = f2bf(a0[r] + bq[oc0]);
      Qbf[(size_t)orow * DE + oc1] = f2bf(a1[r] + bq[oc1]);
    }
    return;
  }
  if (f >= 256) {                  // ---- mean partials ----
    int b = f - 256;
    int r0 = b * 32;
    float s = 0.f;
    for (int r = 0; r < 32; ++r) s += z[(size_t)(r0 + r) * DE + tid];
    mup[b * DE + tid] = s;
    return;
  }
  // ---- Z^T Z 64x64 tile over a 128-row slice, plain store to A_part[slice] ----
  __shared__ float As[16][68];
  __shared__ float Bs[16][68];
  int tx = tid & 15, ty = tid >> 4;
  int i0 = (f & 3) * 64, j0 = ((f >> 2) & 3) * 64;
  int slice = f >> 4;
  int nbase = slice * 128;
  float acc[4][4] = {};
  for (int nt = 0; nt < 8; ++nt) {
    int n0 = nbase + nt * 16;
    for (int e = tid; e < 1024; e += 256) {
      int c = e & 63, nn = e >> 6;
      As[nn][c] = z[(size_t)(n0 + nn) * DE + i0 + c];
      Bs[nn][c] = z[(size_t)(n0 + nn) * DE + j0 + c];
    }
    __syncthreads();
#pragma unroll
    for (int nn = 0; nn < 16; ++nn) {
      float4 a4 = *(const float4*)&As[nn][ty * 4];
      float4 b4 = *(const float4*)&Bs[nn][tx * 4];
      acc[0][0] += a4.x*b4.x; acc[0][1] += a4.x*b4.y; acc[0][2] += a4.x*b4.z; acc[0][3] += a4.x*b4.w;
      acc[1][0] += a4.y*b4.x; acc[1][1] += a4.y*b4.y; acc[1][2] += a4.y*b4.z; acc[1][3] += a4.y*b4.w;
      acc[2][0] += a4.z*b4.x; acc[2][1] += a4.z*b4.y; acc[2][2] += a4.z*b4.z; acc[2][3] += a4.z*b4.w;
      acc[3][0] += a4.w*b4.x; acc[3][1] += a4.w*b4.y; acc[3][2] += a4.w*b4.z; acc[3][3] += a4.w*b4.w;
    }
    __syncthreads();
  }
  float* dstA = &Apart[(size_t)slice * 65536];
  for (int r = 0; r < 4; ++r) {
    int i = i0 + ty * 4 + r;
    for (int c = 0; c < 4; ++c) {
      int j = j0 + tx * 4 + c;
      dstA[(size_t)i * DE + j] = acc[r][c];
    }
  }
}

// ---------------- 16-way tree reduction of cov partials: A = sum_s A_part[s] ----------------
__global__ __launch_bounds__(256) void covred_kernel(const float* __restrict__ Apart,
                                                     float* __restrict__ A) {
  int e0 = (blockIdx.x * 256 + threadIdx.x) * 4;
  float4 s = {0.f, 0.f, 0.f, 0.f};
#pragma unroll
  for (int sl = 0; sl < 16; ++sl) {
    float4 v = *(const float4*)&Apart[(size_t)sl * 65536 + e0];
    s.x += v.x; s.y += v.y; s.z += v.z; s.w += v.w;
  }
  *(float4*)&A[e0] = s;
}

// ---------------- dist: Mahalanobis via quadratic form, E built on-the-fly ----------------
// d = c^T X c with X = I + E + E^2  ==  c.c + c.u + u.u where u = E c (E symmetric).
__global__ __launch_bounds__(256) void dist_kernel(const float* __restrict__ z,
                                                   const float* __restrict__ rmean,
                                                   const float* __restrict__ mup,
                                                   const float* __restrict__ ZtZ,
                                                   const float* __restrict__ rcov,
                                                   float* __restrict__ dist) {
  __shared__ float cc[8][256];
  __shared__ float mus[256];
  __shared__ float4 red[256];
  int n0 = blockIdx.x * 8, i = threadIdx.x;
  float s = 0.f;
  for (int b = 0; b < 64; ++b) s += mup[b * DE + i];
  mus[i] = s;
  float rmi = 0.99f * rmean[i] + 0.01f * s * (1.0f / (float)NB);
#pragma unroll
  for (int r = 0; r < 8; ++r) cc[r][i] = z[(size_t)(n0 + r) * DE + i] - rmi;
  __syncthreads();
  const float c1 = 0.01f / (float)(NB - 1);
  const float invN = 1.0f / (float)NB;
  float musi = mus[i];
  float u[8] = {};
#pragma unroll 4
  for (int j = 0; j < DE; ++j) {
    float base = 0.99f * rcov[(size_t)j * DE + i] +
                 c1 * (ZtZ[(size_t)j * DE + i] - mus[j] * musi * invN);
    float e = -base;
    if (j == i) e += 1.0f - 1e-6f;
#pragma unroll
    for (int r = 0; r < 8; ++r) u[r] += e * cc[r][j];
  }
  // rows 0..3
  {
    float4 v;
    v.x = cc[0][i] * (cc[0][i] + u[0]) + u[0] * u[0];
    v.y = cc[1][i] * (cc[1][i] + u[1]) + u[1] * u[1];
    v.z = cc[2][i] * (cc[2][i] + u[2]) + u[2] * u[2];
    v.w = cc[3][i] * (cc[3][i] + u[3]) + u[3] * u[3];
    red[i] = v;
    __syncthreads();
    for (int sH = 128; sH > 0; sH >>= 1) {
      if (i < sH) {
        float4 a = red[i], b = red[i + sH];
        a.x += b.x; a.y += b.y; a.z += b.z; a.w += b.w;
        red[i] = a;
      }
      __syncthreads();
    }
    if (i < 4) {
      float4 tt = red[0];
      float d = (i == 0) ? tt.x : (i == 1) ? tt.y : (i == 2) ? tt.z : tt.w;
      dist[n0 + i] = sqrtf(fmaxf(d, 1e-8f));
    }
    __syncthreads();
  }
  // rows 4..7
  {
    float4 v;
    v.x = cc[4][i] * (cc[4][i] + u[4]) + u[4] * u[4];
    v.y = cc[5][i] * (cc[5][i] + u[5]) + u[5] * u[5];
    v.z = cc[6][i] * (cc[6][i] + u[6]) + u[6] * u[6];
    v.w = cc[7][i] * (cc[7][i] + u[7]) + u[7] * u[7];
    red[i] = v;
    __syncthreads();
    for (int sH = 128; sH > 0; sH >>= 1) {
      if (i < sH) {
        float4 a = red[i], b = red[i + sH];
        a.x += b.x; a.y += b.y; a.z += b.z; a.w += b.w;
        red[i] = a;
      }
      __syncthreads();
    }
    if (i < 4) {
      float4 tt = red[0];
      float d = (i == 0) ? tt.x : (i == 1) ? tt.y : (i == 2) ? tt.z : tt.w;
      dist[n0 + 4 + i] = sqrtf(fmaxf(d, 1e-8f));
    }
  }
}

// ---------------- fused update: wave reductions, small-C wave sort, two-level extraction ----------------
__global__ __launch_bounds__(1024) void update_kernel(const float* __restrict__ dist,
                                                      const int* __restrict__ labels,
                                                      const float* __restrict__ weights,
                                                      const float* __restrict__ z,
                                                      float* __restrict__ memory) {
  __shared__ unsigned long long ikeys[NB];
  __shared__ unsigned long long ck[CAND_CAP];
  __shared__ unsigned long long gmin[16];
  __shared__ int slots[CAND_CAP], srcs[CAND_CAP];
  __shared__ float smin[16], smax[16];
  __shared__ int scnt[16];
  __shared__ float s_kl, s_dmin, s_inv;
  __shared__ int s_ccnt, s_m, s_stop, s_bg;
  int t = threadIdx.x;
  int wid = t >> 6, lane = t & 63;

  float mn = 1e30f, mx = -1e30f; int c1 = 0;
  for (int n = t; n < NB; n += 1024) {
    float d = dist[n];
    mn = fminf(mn, d); mx = fmaxf(mx, d);
    c1 += labels[n];
  }
#pragma unroll
  for (int o = 32; o > 0; o >>= 1) {
    mn = fminf(mn, __shfl_xor(mn, o, 64));
    mx = fmaxf(mx, __shfl_xor(mx, o, 64));
    c1 += __shfl_xor(c1, o, 64);
  }
  if (lane == 0) { smin[wid] = mn; smax[wid] = mx; scnt[wid] = c1; }
  if (t == 0) { s_ccnt = 0; s_m = 0; s_stop = 0; }
  __syncthreads();
  if (t == 0) {
    float a = 1e30f, b = -1e30f; int cc = 0;
    for (int i = 0; i < 16; ++i) { a = fminf(a, smin[i]); b = fmaxf(b, smax[i]); cc += scnt[i]; }
    float p1 = (float)cc / (float)NB;
    float p0 = (float)(NB - cc) / (float)NB;
    float kl = p0 * logf(fmaxf(2.f * p0, 1e-8f)) + p1 * logf(fmaxf(2.f * p1, 1e-8f));
    s_kl = fmaxf(kl, 0.f);
    s_dmin = a;
    s_inv = 1.0f / (b - a + 1e-8f);
  }
  __syncthreads();
  float kl = s_kl;

  for (int n = t; n < NB; n += 1024) {
    float imp = (1.0f + (dist[n] - s_dmin) * s_inv) * kl;
    ikeys[n] = ((unsigned long long)(unsigned)(~__float_as_uint(imp)) << 32) | (unsigned)n;
  }
  float thresh = 2.f * kl;
  for (int j = t; j < MEMN; j += 1024) {
    float wv = weights[j];
    if (wv < thresh) {
      int p = atomicAdd(&s_ccnt, 1);
      if (p < CAND_CAP) ck[p] = ((unsigned long long)__float_as_uint(wv) << 32) | (unsigned)j;
    }
  }
  __syncthreads();
  int C = s_ccnt; if (C > CAND_CAP) C = CAND_CAP;
  for (int i = t; i < CAND_CAP; i += 1024)
    if (i >= C) ck[i] = 0xFFFFFFFFFFFFFFFFULL;
  __syncthreads();
  if (C <= 64) {
    // single-wave rank sort, no barriers inside (wave 0 only)
    if (wid == 0) {
      unsigned long long key = (lane < C) ? ck[lane] : 0xFFFFFFFFFFFFFFFFULL;
      int rank = 0;
      for (int j = 0; j < 64; ++j) {
        unsigned long long o = (unsigned long long)__shfl((long long)key, j, 64);
        rank += (o < key) || (o == key && j < lane);
      }
      if (lane < C) ck[rank] = key;
    }
    __syncthreads();
  } else {
    bitonic_sort_u64(ck, CAND_CAP, t, 1024);
  }

  // group minima: wave wid owns ikeys[wid*128 .. wid*128+127]
  {
    unsigned long long a = ikeys[wid * 128 + lane];
    unsigned long long b = ikeys[wid * 128 + 64 + lane];
    unsigned long long mm = a < b ? a : b;
#pragma unroll
    for (int o = 32; o > 0; o >>= 1) {
      unsigned long long ot = (unsigned long long)__shfl_xor((long long)mm, o, 64);
      if (ot < mm) mm = ot;
    }
    if (lane == 0) gmin[wid] = mm;
  }
  __syncthreads();

  float prevv = 0.f;   // thread 0 only
  for (int i = 0; i < C; ++i) {
    if (t == 0) {
      unsigned long long best = 0xFFFFFFFFFFFFFFFFULL;
      for (int g = 0; g < 16; ++g) if (gmin[g] < best) best = gmin[g];
      float im = __uint_as_float(~(unsigned)(best >> 32));
      float wv = __uint_as_float((unsigned)(ck[i] >> 32));
      bool ok = (im > wv) && (i == 0 || prevv >= wv);
      if (ok) {
        int idx = (int)(best & 0xffffffffULL);
        slots[s_m] = (int)(ck[i] & 0xffffffffULL);
        srcs[s_m]  = idx;
        s_m++;
        prevv = im;
        ikeys[idx] = 0xFFFFFFFFFFFFFFFFULL;
        s_bg = idx >> 7;
      } else {
        s_stop = 1; s_bg = -1;
      }
    }
    __syncthreads();
    if (s_stop) break;
    if (wid == s_bg) {
      unsigned long long a = ikeys[wid * 128 + lane];
      unsigned long long b = ikeys[wid * 128 + 64 + lane];
      unsigned long long mm = a < b ? a : b;
#pragma unroll
      for (int o = 32; o > 0; o >>= 1) {
        unsigned long long ot = (unsigned long long)__shfl_xor((long long)mm, o, 64);
        if (ot < mm) mm = ot;
      }
      if (lane == 0) gmin[wid] = mm;
    }
    __syncthreads();
  }
  int m = s_m;
  for (int e = t; e < m * DE; e += 1024) {
    int i = e >> 8, d = e & 255;
    memory[(size_t)slots[i] * DE + d] = z[(size_t)srcs[i] * DE + d];
  }
}

// ---------------- K/V projection GEMMs (Q moved to covmu launch) ----------------
__global__ __launch_bounds__(256, 1) void qkv_kernel(
    const float* __restrict__ memory,
    const float* __restrict__ Wk, const float* __restrict__ bk,
    const float* __restrict__ Wv, const float* __restrict__ bv,
    unsigned short* __restrict__ Kbf, unsigned short* __restrict__ Vtb) {
  __shared__ unsigned short Bsh[64 * 264];
  int flat = blockIdx.x;
  int tid = threadIdx.x;
  int w = tid >> 6, lane = tid & 63;
  int m = lane & 31, h = lane >> 5;

  if (flat < 128) {                // ---- K = mem@Wk^T+bk: A once, loop 4 B-tiles ----
    int gx = flat;                 // 0..127
    int arow = gx * 128 + w * 32 + m;
    short8 af[16];
#pragma unroll
    for (int kc = 0; kc < 16; ++kc) {
      const float* src = &memory[(size_t)arow * DE + kc * 16 + h * 8];
      af[kc] = pack8_bf16(*(const float4*)&src[0], *(const float4*)&src[4]);
    }
    for (int g4 = 0; g4 < 4; ++g4) {
      int n0 = g4 * 64;
      __syncthreads();             // previous tile's reads complete
      {
        int r = tid >> 2, q = tid & 3;
        const float* src = &Wk[(size_t)(n0 + r) * DE + q * 64];
        unsigned short* dst = &Bsh[r * 264 + q * 64];
#pragma unroll
        for (int j = 0; j < 8; ++j)
          *(short8*)&dst[j * 8] = pack8_bf16(*(const float4*)&src[j * 8],
                                             *(const float4*)&src[j * 8 + 4]);
      }
      __syncthreads();
      float16 a0 = {}, a1 = {};
#pragma unroll
      for (int kc = 0; kc < 16; ++kc) {
        short8 b0 = *(const short8*)&Bsh[(0 * 32 + m) * 264 + kc * 16 + h * 8];
        short8 b1 = *(const short8*)&Bsh[(1 * 32 + m) * 264 + kc * 16 + h * 8];
        a0 = __builtin_amdgcn_mfma_f32_32x32x16_bf16(af[kc], b0, a0, 0, 0, 0);
        a1 = __builtin_amdgcn_mfma_f32_32x32x16_bf16(af[kc], b1, a1, 0, 0, 0);
      }
#pragma unroll
      for (int r = 0; r < 16; ++r) {
        int rr = (r & 3) + 8 * (r >> 2) + 4 * h;
        int orow = gx * 128 + w * 32 + rr;
        int oc0 = n0 + m, oc1 = n0 + 32 + m;
        Kbf[(size_t)orow * DE + oc0] = f2bf(a0[r] + bk[oc0]);
        Kbf[(size_t)orow * DE + oc1] = f2bf(a1[r] + bk[oc1]);
      }
    }
  } else {                         // ---- Vt = Wv@mem^T+bv: B once, loop 2 A-halves ----
    int gy = flat - 128;           // 0..255
    int n0 = gy * 64;
    {
      int r = tid >> 2, q = tid & 3;
      const float* src = &memory[(size_t)(n0 + r) * DE + q * 64];
      unsigned short* dst = &Bsh[r * 264 + q * 64];
#pragma unroll
      for (int j = 0; j < 8; ++j)
        *(short8*)&dst[j * 8] = pack8_bf16(*(const float4*)&src[j * 8],
                                           *(const float4*)&src[j * 8 + 4]);
    }
    __syncthreads();
    for (int gxv = 0; gxv < 2; ++gxv) {
      short8 af[16];
#pragma unroll
      for (int kc = 0; kc < 16; ++kc) {
        const float* src = &Wv[(size_t)(gxv * 128 + w * 32 + m) * DE + kc * 16 + h * 8];
        af[kc] = pack8_bf16(*(const float4*)&src[0], *(const float4*)&src[4]);
      }
      float16 a0 = {}, a1 = {};
#pragma unroll
      for (int kc = 0; kc < 16; ++kc) {
        short8 b0 = *(const short8*)&Bsh[(0 * 32 + m) * 264 + kc * 16 + h * 8];
        short8 b1 = *(const short8*)&Bsh[(1 * 32 + m) * 264 + kc * 16 + h * 8];
        a0 = __builtin_amdgcn_mfma_f32_32x32x16_bf16(af[kc], b0, a0, 0, 0, 0);
        a1 = __builtin_amdgcn_mfma_f32_32x32x16_bf16(af[kc], b1, a1, 0, 0, 0);
      }
#pragma unroll
      for (int r = 0; r < 16; ++r) {
        int rr = (r & 3) + 8 * (r >> 2) + 4 * h;
        int orow = gxv * 128 + w * 32 + rr;
        int oc0 = n0 + m, oc1 = n0 + 32 + m;
        Vtb[(size_t)(oc0 >> 5) * 8192 + (size_t)orow * 32 + (oc0 & 31)] = f2bf(a0[r] + bv[orow]);
        Vtb[(size_t)(oc1 >> 5) * 8192 + (size_t)orow * 32 + (oc1 & 31)] = f2bf(a1[r] + bv[orow]);
      }
    }
  }
}

// ---------------- MFMA flash attention: dh-merged, FSPL=32, T12 in-reg softmax ----------------
// Round-9 structure (best measured). 264-pad Ks layout retained.
__global__ __launch_bounds__(512, 2) void flash_kernel(
    const unsigned short* __restrict__ Qb, const unsigned short* __restrict__ Kb,
    const unsigned short* __restrict__ Vtb, unsigned short* __restrict__ Opb,
    float* __restrict__ Lp) {
  __shared__ unsigned short Ks[32 * 264];
  __shared__ unsigned short Vs[256 * 40];

  int tid = threadIdx.x;
  int w = tid >> 6, lane = tid & 63;
  int m = lane & 31, h = lane >> 5;
  int sp = blockIdx.x, qg = blockIdx.y;
  int myrow = qg * 256 + w * 32 + m;

  short8 qf[16];
#pragma unroll
  for (int kc = 0; kc < 16; ++kc)
    qf[kc] = *(const short8*)&Qb[(size_t)myrow * DE + kc * 16 + h * 8];

  float16 O[8] = {};
  float lacc = 0.f;

  short8 kreg[2], vreg[2];
#define LOAD_TILES(kb_)                                                              \
  {                                                                                  \
    int kb = (kb_);                                                                  \
    _Pragma("unroll")                                                                \
    for (int i = 0; i < 2; ++i) {                                                    \
      int c = i * 512 + tid, kr = c >> 5, kcol = c & 31;                             \
      kreg[i] = *(const short8*)&Kb[(size_t)(kb + kr) * DE + kcol * 8];              \
    }                                                                                \
    const unsigned short* vg = &Vtb[(size_t)((kb) >> 5) * 8192];                     \
    _Pragma("unroll")                                                                \
    for (int i = 0; i < 2; ++i) {                                                    \
      int c = i * 512 + tid;                                                         \
      vreg[i] = *(const short8*)&vg[c * 8];                                          \
    }                                                                                \
  }
#define STORE_TILES()                                                                \
  {                                                                                  \
    _Pragma("unroll")                                                                \
    for (int i = 0; i < 2; ++i) {                                                    \
      int c = i * 512 + tid, kr = c >> 5, kcol = c & 31;                             \
      *(short8*)&Ks[kr * 264 + kcol * 8] = kreg[i];                                  \
    }                                                                                \
    _Pragma("unroll")                                                                \
    for (int i = 0; i < 2; ++i) {                                                    \
      int c = i * 512 + tid, dr = c >> 2, dc = c & 3;                                \
      *(short8*)&Vs[dr * 40 + dc * 8] = vreg[i];                                     \
    }                                                                                \
  }

  LOAD_TILES(sp * FKPS);

  for (int it = 0; it < FIT; ++it) {
    __syncthreads();               // LDS free (previous compute done)
    STORE_TILES();
    if (it + 1 < FIT) LOAD_TILES(sp * FKPS + (it + 1) * 32);
    __syncthreads();               // LDS ready

    // QK^T with SWAPPED operands: A=K-frag, B=Q-frag -> lane (m,h) holds
    // S[k=crow(r,h)][qrow=m]: the P-row of q-row m is lane-local.
    float16 s = {};
    __builtin_amdgcn_s_setprio(1);
#pragma unroll
    for (int kc = 0; kc < 16; ++kc) {
      short8 b0 = *(const short8*)&Ks[m * 264 + kc * 16 + h * 8];
      s = __builtin_amdgcn_mfma_f32_32x32x16_bf16(b0, qf[kc], s, 0, 0, 0);
    }
    __builtin_amdgcn_s_setprio(0);

    // p[r] = P[m][k=crow(r,h)]; exp(0.625*s - 11.0903549) == exp2(0.90168440*s - 16)
    float p[16];
#pragma unroll
    for (int r = 0; r < 16; ++r)
      p[r] = exp2f(fmaf(s[r], 0.90168440f, -16.0f));

    lacc += ((p[0] + p[1]) + (p[2] + p[3])) + ((p[4] + p[5]) + (p[6] + p[7])) +
            ((p[8] + p[9]) + (p[10] + p[11])) + ((p[12] + p[13]) + (p[14] + p[15]));

    unsigned c0 = cvtpk_bf16(p[0],  p[1]);
    unsigned c1 = cvtpk_bf16(p[2],  p[3]);
    unsigned c2 = cvtpk_bf16(p[4],  p[5]);
    unsigned c3 = cvtpk_bf16(p[6],  p[7]);
    unsigned c4 = cvtpk_bf16(p[8],  p[9]);
    unsigned c5 = cvtpk_bf16(p[10], p[11]);
    unsigned c6 = cvtpk_bf16(p[12], p[13]);
    unsigned c7 = cvtpk_bf16(p[14], p[15]);
    halfswap(c0, c2, h);
    halfswap(c1, c3, h);
    halfswap(c4, c6, h);
    halfswap(c5, c7, h);
    uint4v w0v = {c0, c1, c2, c3};
    uint4v w1v = {c4, c5, c6, c7};
    short8 pa0 = __builtin_bit_cast(short8, w0v);
    short8 pa1 = __builtin_bit_cast(short8, w1v);

    __builtin_amdgcn_s_setprio(1);
#pragma unroll
    for (int ct = 0; ct < 8; ++ct) {
      short8 vb0 = *(const short8*)&Vs[(ct * 32 + m) * 40 + h * 8];
      short8 vb1 = *(const short8*)&Vs[(ct * 32 + m) * 40 + 16 + h * 8];
      O[ct] = __builtin_amdgcn_mfma_f32_32x32x16_bf16(pa0, vb0, O[ct], 0, 0, 0);
      O[ct] = __builtin_amdgcn_mfma_f32_32x32x16_bf16(pa1, vb1, O[ct], 0, 0, 0);
    }
    __builtin_amdgcn_s_setprio(0);
  }
#undef LOAD_TILES
#undef STORE_TILES

  size_t ob = ((size_t)sp * NB + qg * 256 + w * 32) * DE;
#pragma unroll
  for (int ct = 0; ct < 8; ++ct)
#pragma unroll
    for (int r = 0; r < 16; ++r) {
      int rr = (r & 3) + 8 * (r >> 2) + 4 * h;
      Opb[ob + (size_t)rr * DE + ct * 32 + m] = f2bf(O[ct][r]);
    }
  float ltot = lacc + __shfl_xor(lacc, 32, 64);
  if (h == 0)
    Lp[sp * NB + qg * 256 + w * 32 + m] = ltot;
}

// combine: vectorized short8 Opb reads (16 B/lane), 8 rows/block, grid 256.
__global__ __launch_bounds__(256) void combine_kernel(const float* __restrict__ z,
                                                      const unsigned short* __restrict__ Opb,
                                                      const float* __restrict__ Lp,
                                                      float* __restrict__ out) {
  int t = threadIdx.x;
  int n = blockIdx.x * 8 + (t >> 5);
  int c0 = (t & 31) * 8;
  float num[8] = {};
  float den = 0.f;
#pragma unroll
  for (int s = 0; s < FSPL; ++s) {
    den += Lp[s * NB + n];
    short8 v = *(const short8*)&Opb[((size_t)s * NB + n) * DE + c0];
#pragma unroll
    for (int j = 0; j < 8; ++j) num[j] += bf2f((unsigned short)v[j]);
  }
  size_t base = (size_t)n * DE + c0;
  float4 o0, o1;
  o0.x = z[base + 0] + 0.5f * num[0] / den;
  o0.y = z[base + 1] + 0.5f * num[1] / den;
  o0.z = z[base + 2] + 0.5f * num[2] / den;
  o0.w = z[base + 3] + 0.5f * num[3] / den;
  o1.x = z[base + 4] + 0.5f * num[4] / den;
  o1.y = z[base + 5] + 0.5f * num[5] / den;
  o1.z = z[base + 6] + 0.5f * num[6] / den;
  o1.w = z[base + 7] + 0.5f * num[7] / den;
  *(float4*)&out[base] = o0;
  *(float4*)&out[base + 4] = o1;
}

// ---------------- launcher: 7 kernels, stream-ordered ----------------
extern "C" void kernel_launch(void* const* d_in, const int* in_sizes, int n_in,
                              void* d_out, int out_size, void* d_ws, size_t ws_size,
                              hipStream_t stream) {
  (void)in_sizes; (void)n_in; (void)out_size; (void)ws_size;
  const float* z       = (const float*)d_in[0];
  const int*   labels  = (const int*)d_in[1];
  float*       memory  = (float*)d_in[2];
  const float* weights = (const float*)d_in[3];
  const float* rmean   = (const float*)d_in[4];
  const float* rcov    = (const float*)d_in[5];
  const float* Wq      = (const float*)d_in[6];
  const float* bq      = (const float*)d_in[7];
  const float* Wk      = (const float*)d_in[8];
  const float* bk      = (const float*)d_in[9];
  const float* Wv      = (const float*)d_in[10];
  const float* bv      = (const float*)d_in[11];
  float* out = (float*)d_out;
  float* ws  = (float*)d_ws;

  unsigned short* Qbf = (unsigned short*)(ws + OFF_QB);
  unsigned short* Kbf = (unsigned short*)(ws + OFF_KB);
  unsigned short* Vtb = (unsigned short*)(ws + OFF_VTB);
  float* Lp           = ws + OFF_LP;
  unsigned short* Opb = (unsigned short*)(ws + OFF_OPB);
  float* SB    = ws + OFF_OPB;    // stats overlay (dead before flash writes Opb)
  float* Apart = SB + SO_APART;
  float* A     = SB + SO_A;
  float* mup   = SB + SO_MUP;
  float* dist  = SB + SO_DIST;

  covmu_kernel<<<384, 256, 0, stream>>>(z, Apart, mup, Wq, bq, Qbf);
  covred_kernel<<<64, 256, 0, stream>>>(Apart, A);
  dist_kernel<<<NB / 8, 256, 0, stream>>>(z, rmean, mup, A, rcov, dist);
  update_kernel<<<1, 1024, 0, stream>>>(dist, labels, weights, z, memory);
  qkv_kernel<<<384, 256, 0, stream>>>(memory, Wk, bk, Wv, bv, Kbf, Vtb);
  flash_kernel<<<dim3(FSPL, NB / 256), 512, 0, stream>>>(Qbf, Kbf, Vtb, Opb, Lp);
  combine_kernel<<<NB / 8, 256, 0, stream>>>(z, Opb, Lp, out);
}